// Round 6
// baseline (86.824 us; speedup 1.0000x reference)
//
#include <hip/hip_runtime.h>

#define NQ 4096
#define MK 4096
#define DKC 512
#define DVC 512
#define SCALE 0.044151079f  // 1/sqrt(513)

typedef __attribute__((ext_vector_type(8))) short short8;
typedef __attribute__((ext_vector_type(4))) float f32x4;

__device__ __forceinline__ unsigned short f2bf(float x) {
  unsigned u = __float_as_uint(x);
  u += 0x7fffu + ((u >> 16) & 1u);
  return (unsigned short)(u >> 16);
}
__device__ __forceinline__ float bf2f(unsigned short h) {
  return __uint_as_float((unsigned)h << 16);
}

#define GLL16(g, l)                                                        \
  __builtin_amdgcn_global_load_lds(                                        \
      (const __attribute__((address_space(1))) unsigned int*)(g),          \
      (__attribute__((address_space(3))) unsigned int*)(l), 16, 0, 0)

// ---------------- prep: query -> bf16, q_att = rowdot(query, q_k) ----------------
__global__ void prep_q(const float* __restrict__ query, const float* __restrict__ q_k,
                       unsigned short* __restrict__ Qb, float* __restrict__ qatt) {
  int n = blockIdx.x * 4 + (threadIdx.x >> 6);
  int lane = threadIdx.x & 63;
  const float4* qr = (const float4*)(query + (size_t)n * DKC + lane * 8);
  const float4* kr = (const float4*)(q_k + (size_t)n * DKC + lane * 8);
  float4 a0 = qr[0], a1 = qr[1];
  float4 b0 = kr[0], b1 = kr[1];
  float dot = a0.x * b0.x + a0.y * b0.y + a0.z * b0.z + a0.w * b0.w +
              a1.x * b1.x + a1.y * b1.y + a1.z * b1.z + a1.w * b1.w;
  unsigned short h[8] = {f2bf(a0.x), f2bf(a0.y), f2bf(a0.z), f2bf(a0.w),
                         f2bf(a1.x), f2bf(a1.y), f2bf(a1.z), f2bf(a1.w)};
  *(short8*)(Qb + (size_t)n * DKC + lane * 8) = *(short8*)h;
#pragma unroll
  for (int off = 1; off < 64; off <<= 1) dot += __shfl_xor(dot, off, 64);
  if (lane == 0) qatt[n] = dot;
}

// ---------------- prep: key -> bf16 ----------------
__global__ void prep_k(const float* __restrict__ key, unsigned short* __restrict__ Kb) {
  int i = blockIdx.x * blockDim.x + threadIdx.x;  // one per 8 elements
  const float4* src = (const float4*)key + (size_t)i * 2;
  float4 a0 = src[0], a1 = src[1];
  unsigned short h[8] = {f2bf(a0.x), f2bf(a0.y), f2bf(a0.z), f2bf(a0.w),
                         f2bf(a1.x), f2bf(a1.y), f2bf(a1.z), f2bf(a1.w)};
  *(short8*)(Kb + (size_t)i * 8) = *(short8*)h;
}

// ---------------- prep: value -> bf16 transposed Vt[d][m] ----------------
__global__ void prep_vt(const float* __restrict__ value, unsigned short* __restrict__ Vt) {
  __shared__ float t[32][33];
  int tx = threadIdx.x & 31, ty = threadIdx.x >> 5;  // 32x8
  int m0 = blockIdx.x * 32;
  int d0 = blockIdx.y * 32;
#pragma unroll
  for (int i = 0; i < 4; ++i)
    t[ty + i * 8][tx] = value[(size_t)(m0 + ty + i * 8) * DVC + d0 + tx];
  __syncthreads();
#pragma unroll
  for (int i = 0; i < 4; ++i)
    Vt[(size_t)(d0 + ty + i * 8) * MK + m0 + tx] = f2bf(t[tx][ty + i * 8]);
}

// ---------------- gemm_s: S[4096][4096] bf16 = Qb * Kb^T (K=512) ----------------
__global__ __launch_bounds__(256, 3) void gemm_s(const unsigned short* __restrict__ Qb,
                                                 const unsigned short* __restrict__ Kb,
                                                 unsigned short* __restrict__ S) {
  __shared__ __align__(16) char lds[32768];  // A@0 (16K), B@16K (16K); epilogue reuses all
  const int tid = threadIdx.x;
  const int wid = tid >> 6, lane = tid & 63, lr = lane & 15, lh = lane >> 4;
  const int wm = wid >> 1, wn = wid & 1;

  int bid = blockIdx.x;                    // 1024 WGs, bijective XCD swizzle (1024%8==0)
  int swz = (bid & 7) * 128 + (bid >> 3);
  const int tm = swz >> 5, tn = swz & 31;
  const size_t m0 = (size_t)tm * 128, n0 = (size_t)tn * 128;

  f32x4 acc[4][4];
#pragma unroll
  for (int i = 0; i < 4; ++i)
#pragma unroll
    for (int j = 0; j < 4; ++j) acc[i][j] = (f32x4){0.f, 0.f, 0.f, 0.f};

  const char* abase = (const char*)Qb + m0 * 1024;  // row stride 1024 B
  const char* bbase = (const char*)Kb + n0 * 1024;

  for (int ks = 0; ks < 8; ++ks) {
    const int kb = ks * 128;  // 64 elems = 128 B per K-step
    {
      char* al = lds;
      char* bl = lds + 16384;
#pragma unroll
      for (int s = 0; s < 4; ++s) {
        int obase = wid * 4096 + s * 1024;  // wave-uniform LDS base; HW adds lane*16
        int o = obase + lane * 16;
        int row = o >> 7;                                 // 128 B per LDS row
        int colg = ((o >> 4) & 7) ^ (row & 7);            // inverse-swizzled source granule
        GLL16(abase + (size_t)row * 1024 + kb + colg * 16, al + obase);
        GLL16(bbase + (size_t)row * 1024 + kb + colg * 16, bl + obase);
      }
    }
    __syncthreads();
#pragma unroll
    for (int kk = 0; kk < 2; ++kk) {
      short8 af[4], bf[4];
#pragma unroll
      for (int i = 0; i < 4; ++i) {
        int ar = wm * 64 + i * 16 + lr;
        af[i] = *(const short8*)(lds + ar * 128 + ((((kk << 2) + lh) ^ (lr & 7)) << 4));
        int br = wn * 64 + i * 16 + lr;
        bf[i] = *(const short8*)(lds + 16384 + br * 128 + ((((kk << 2) + lh) ^ (lr & 7)) << 4));
      }
#pragma unroll
      for (int i = 0; i < 4; ++i)
#pragma unroll
        for (int j = 0; j < 4; ++j)
          acc[i][j] = __builtin_amdgcn_mfma_f32_16x16x32_bf16(af[i], bf[j], acc[i][j], 0, 0, 0);
    }
    __syncthreads();
  }

  // epilogue: bf16 bounce through LDS [128][128], then fully-coalesced 16B stores
  unsigned short* sl = (unsigned short*)lds;
#pragma unroll
  for (int i = 0; i < 4; ++i)
#pragma unroll
    for (int j = 0; j < 4; ++j)
#pragma unroll
      for (int r = 0; r < 4; ++r) {
        int m = wm * 64 + i * 16 + lh * 4 + r;
        int n = wn * 64 + j * 16 + lr;
        sl[m * 128 + n] = f2bf(acc[i][j][r]);
      }
  __syncthreads();
#pragma unroll
  for (int i = 0; i < 8; ++i) {
    int o = i * 4096 + tid * 16;
    int row = o >> 8, colb = o & 255;  // 256 B per bf16 tile row
    *(uint4*)((char*)S + (m0 + row) * 8192 + n0 * 2 + colb) = *(const uint4*)((const char*)sl + o);
  }
}

// ---------------- softmax_rows: in-place S -> P' = softmax_row/denom (bf16) ----------------
__global__ __launch_bounds__(256) void softmax_rows(unsigned short* __restrict__ S,
                                                    const float* __restrict__ qatt) {
  __shared__ float red[8];
  const int n = blockIdx.x;
  const int t = threadIdx.x;
  const int wv = t >> 6, lane = t & 63;
  unsigned short* row = S + (size_t)n * MK;
  short8 v0 = *(const short8*)(row + t * 16);
  short8 v1 = *(const short8*)(row + t * 16 + 8);
  float f[16];
#pragma unroll
  for (int j = 0; j < 8; ++j) {
    f[j] = bf2f((unsigned short)v0[j]) * SCALE;
    f[8 + j] = bf2f((unsigned short)v1[j]) * SCALE;
  }
  float mx = f[0];
#pragma unroll
  for (int j = 1; j < 16; ++j) mx = fmaxf(mx, f[j]);
#pragma unroll
  for (int off = 1; off < 64; off <<= 1) mx = fmaxf(mx, __shfl_xor(mx, off, 64));
  if (lane == 0) red[wv] = mx;
  __syncthreads();
  mx = fmaxf(fmaxf(red[0], red[1]), fmaxf(red[2], red[3]));
  float qa = qatt[n] * SCALE;
  mx = fmaxf(mx, qa);
  float e[16], s = 0.f;
#pragma unroll
  for (int j = 0; j < 16; ++j) {
    e[j] = __expf(f[j] - mx);
    s += e[j];
  }
#pragma unroll
  for (int off = 1; off < 64; off <<= 1) s += __shfl_xor(s, off, 64);
  if (lane == 0) red[4 + wv] = s;
  __syncthreads();
  float denom = red[4] + red[5] + red[6] + red[7] + __expf(qa - mx);
  float inv = 1.0f / denom;
  unsigned short h[16];
#pragma unroll
  for (int j = 0; j < 16; ++j) h[j] = f2bf(e[j] * inv);
  *(short8*)(row + t * 16) = *(short8*)h;
  *(short8*)(row + t * 16 + 8) = *(short8*)(h + 8);
}

// ---------------- gemm_o_part: part[ks][4096][512] f32 = P'(K-slice) * V ----------------
// Split-K=2. Tile 128m x 128n, 8 waves (2wm x 4wn, 64x32 each, 4x2 acc -> 24 FLOP/LDS-byte),
// BK=128, double-buffered LDS (2 x 64KB), counted vmcnt(8) + raw s_barrier.
__global__ __launch_bounds__(512, 1) void gemm_o_part(const unsigned short* __restrict__ P,
                                                      const unsigned short* __restrict__ Vt,
                                                      float* __restrict__ part) {
  __shared__ __align__(16) char lds[131072];  // [A0 32K][B0 32K][A1 32K][B1 32K]
  const int tid = threadIdx.x;
  const int wid = tid >> 6, lane = tid & 63, lr = lane & 15, lh = lane >> 4;
  const int wm = wid >> 2, wn = wid & 3;  // 2 x 4 waves, each 64m x 32n

  int bid = blockIdx.x;                   // 256 WGs, 256%8==0 -> bijective XCD swizzle
  int swz = (bid & 7) * 32 + (bid >> 3);
  const int mt = swz >> 3;                // 32 m-tiles; 8 consecutive swz share A panel
  const int nt = (swz >> 1) & 3;          // 4 n-tiles
  const int ksl = swz & 1;                // 2 K-slices
  const size_t m0 = (size_t)mt * 128, n0 = (size_t)nt * 128;

  f32x4 acc[4][2];
#pragma unroll
  for (int i = 0; i < 4; ++i)
#pragma unroll
    for (int j = 0; j < 2; ++j) acc[i][j] = (f32x4){0.f, 0.f, 0.f, 0.f};

  const char* abase = (const char*)P + m0 * 8192 + (size_t)ksl * 4096;   // +2048 elems
  const char* bbase = (const char*)Vt + n0 * 8192 + (size_t)ksl * 4096;

  // stage K-step ks into buffer b: A 128x128 bf16 (32KB, 256B rows) + B 128x128 (32KB)
  auto stage = [&](int ks, int b) {
    const int kb = ks * 256;  // 128 elems = 256 B
    char* al = lds + b * 65536;
    char* bl = al + 32768;
#pragma unroll
    for (int s = 0; s < 4; ++s) {
      int obase = wid * 4096 + s * 1024;  // 8 waves x 4KB, 1KB per GLL16
      int o = obase + lane * 16;
      int row = o >> 8;                            // 256 B per LDS row
      int colg = ((o >> 4) & 15) ^ (row & 7);      // inverse-swizzled source granule
      GLL16(abase + (size_t)row * 8192 + kb + colg * 16, al + obase);
      GLL16(bbase + (size_t)row * 8192 + kb + colg * 16, bl + obase);
    }
  };

  stage(0, 0);  // prologue: 8 outstanding

  for (int ks = 0; ks < 16; ++ks) {
    const int cur = ks & 1;
    if (ks + 1 < 16) {
      stage(ks + 1, cur ^ 1);                           // 8 more in flight (16 total)
      asm volatile("s_waitcnt vmcnt(8)" ::: "memory");  // current step's 8 landed
    } else {
      asm volatile("s_waitcnt vmcnt(0)" ::: "memory");
    }
    __builtin_amdgcn_s_barrier();
    asm volatile("" ::: "memory");

    const char* al = lds + cur * 65536;
    const char* bl = al + 32768;
#pragma unroll
    for (int kk = 0; kk < 4; ++kk) {
      short8 af[4], bf[2];
#pragma unroll
      for (int i = 0; i < 4; ++i) {
        int ar = wm * 64 + i * 16 + lr;
        af[i] = *(const short8*)(al + ar * 256 + ((((kk << 2) + lh) ^ (ar & 7)) << 4));
      }
#pragma unroll
      for (int j = 0; j < 2; ++j) {
        int br = wn * 32 + j * 16 + lr;
        bf[j] = *(const short8*)(bl + br * 256 + ((((kk << 2) + lh) ^ (br & 7)) << 4));
      }
#pragma unroll
      for (int i = 0; i < 4; ++i)
#pragma unroll
        for (int j = 0; j < 2; ++j)
          acc[i][j] = __builtin_amdgcn_mfma_f32_16x16x32_bf16(af[i], bf[j], acc[i][j], 0, 0, 0);
    }

    asm volatile("" ::: "memory");
    __builtin_amdgcn_s_barrier();  // all waves done reading buf[cur] before overwrite
    asm volatile("" ::: "memory");
  }

  // epilogue: f32 bounce [128][128] (64KB) + coalesced 16B stores to part[ksl]
  float* fl = (float*)lds;
#pragma unroll
  for (int i = 0; i < 4; ++i)
#pragma unroll
    for (int j = 0; j < 2; ++j)
#pragma unroll
      for (int r = 0; r < 4; ++r) {
        int m = wm * 64 + i * 16 + lh * 4 + r;
        int n = wn * 32 + j * 16 + lr;
        fl[m * 128 + n] = acc[i][j][r];
      }
  __builtin_amdgcn_s_barrier();
  asm volatile("" ::: "memory");
  char* pbase = (char*)part + (size_t)ksl * NQ * DVC * 4;
#pragma unroll
  for (int i = 0; i < 8; ++i) {
    int o = i * 8192 + tid * 16;
    int row = o >> 9, colb = o & 511;  // 512 B per f32 tile row (128 floats)
    *(uint4*)(pbase + (m0 + row) * 2048 + n0 * 4 + colb) = *(const uint4*)((const char*)fl + o);
  }
}

// ---------------- combine_o: out = q_v*qa + part0 + part1 ----------------
__global__ __launch_bounds__(256) void combine_o(const float* __restrict__ part,
                                                 const float* __restrict__ qatt,
                                                 const float* __restrict__ q_v,
                                                 float* __restrict__ out) {
  int idx = blockIdx.x * blockDim.x + threadIdx.x;  // one per float4
  int n = idx >> 7;
  int d4 = (idx & 127) * 4;
  float qa = qatt[n];
  size_t off = (size_t)n * DVC + d4;
  float4 p0 = *(const float4*)(part + off);
  float4 p1 = *(const float4*)(part + (size_t)NQ * DVC + off);
  float4 qv = *(const float4*)(q_v + off);
  float4 o;
  o.x = qv.x * qa + p0.x + p1.x;
  o.y = qv.y * qa + p0.y + p1.y;
  o.z = qv.z * qa + p0.z + p1.z;
  o.w = qv.w * qa + p0.w + p1.w;
  *(float4*)(out + off) = o;
}

extern "C" void kernel_launch(void* const* d_in, const int* in_sizes, int n_in,
                              void* d_out, int out_size, void* d_ws, size_t ws_size,
                              hipStream_t stream) {
  const float* query = (const float*)d_in[0];
  const float* q_k = (const float*)d_in[1];
  const float* q_v = (const float*)d_in[2];
  const float* key = (const float*)d_in[3];
  const float* value = (const float*)d_in[4];
  float* out = (float*)d_out;

  char* ws = (char*)d_ws;
  unsigned short* Qb = (unsigned short*)(ws);                 // 4 MB
  unsigned short* Kb = (unsigned short*)(ws + (4u << 20));    // 4 MB
  unsigned short* Vt = (unsigned short*)(ws + (8u << 20));    // 4 MB
  unsigned short* S = (unsigned short*)(ws + (12u << 20));    // 32 MB (S, then P' in-place)
  float* qatt = (float*)(ws + (44u << 20));                   // 16 KB
  float* part = (float*)(ws + (45u << 20));                   // 16 MB (2 x 8 MB f32)

  prep_q<<<dim3(1024), dim3(256), 0, stream>>>(query, q_k, Qb, qatt);
  prep_k<<<dim3(1024), dim3(256), 0, stream>>>(key, Kb);
  prep_vt<<<dim3(128, 16), dim3(256), 0, stream>>>(value, Vt);
  gemm_s<<<dim3(1024), dim3(256), 0, stream>>>(Qb, Kb, S);
  softmax_rows<<<dim3(4096), dim3(256), 0, stream>>>(S, qatt);
  gemm_o_part<<<dim3(256), dim3(512), 0, stream>>>(S, Vt, part);
  combine_o<<<dim3(2048), dim3(256), 0, stream>>>(part, qatt, q_v, out);
}

// Round 7
// 82.622 us; speedup vs baseline: 1.0509x; 1.0509x over previous
//
#include <hip/hip_runtime.h>

#define NQ 4096
#define MK 4096
#define DKC 512
#define DVC 512
#define SCALE 0.044151079f  // 1/sqrt(513)

typedef __attribute__((ext_vector_type(8))) short short8;
typedef __attribute__((ext_vector_type(4))) float f32x4;

__device__ __forceinline__ unsigned short f2bf(float x) {
  unsigned u = __float_as_uint(x);
  u += 0x7fffu + ((u >> 16) & 1u);
  return (unsigned short)(u >> 16);
}
__device__ __forceinline__ float bf2f(unsigned short h) {
  return __uint_as_float((unsigned)h << 16);
}

#define GLL16(g, l)                                                        \
  __builtin_amdgcn_global_load_lds(                                        \
      (const __attribute__((address_space(1))) unsigned int*)(g),          \
      (__attribute__((address_space(3))) unsigned int*)(l), 16, 0, 0)

// ---------------- prep: query -> bf16, q_att = rowdot(query, q_k) ----------------
__global__ void prep_q(const float* __restrict__ query, const float* __restrict__ q_k,
                       unsigned short* __restrict__ Qb, float* __restrict__ qatt) {
  int n = blockIdx.x * 4 + (threadIdx.x >> 6);
  int lane = threadIdx.x & 63;
  const float4* qr = (const float4*)(query + (size_t)n * DKC + lane * 8);
  const float4* kr = (const float4*)(q_k + (size_t)n * DKC + lane * 8);
  float4 a0 = qr[0], a1 = qr[1];
  float4 b0 = kr[0], b1 = kr[1];
  float dot = a0.x * b0.x + a0.y * b0.y + a0.z * b0.z + a0.w * b0.w +
              a1.x * b1.x + a1.y * b1.y + a1.z * b1.z + a1.w * b1.w;
  unsigned short h[8] = {f2bf(a0.x), f2bf(a0.y), f2bf(a0.z), f2bf(a0.w),
                         f2bf(a1.x), f2bf(a1.y), f2bf(a1.z), f2bf(a1.w)};
  *(short8*)(Qb + (size_t)n * DKC + lane * 8) = *(short8*)h;
#pragma unroll
  for (int off = 1; off < 64; off <<= 1) dot += __shfl_xor(dot, off, 64);
  if (lane == 0) qatt[n] = dot;
}

// ---------------- prep: key -> bf16 ----------------
__global__ void prep_k(const float* __restrict__ key, unsigned short* __restrict__ Kb) {
  int i = blockIdx.x * blockDim.x + threadIdx.x;  // one per 8 elements
  const float4* src = (const float4*)key + (size_t)i * 2;
  float4 a0 = src[0], a1 = src[1];
  unsigned short h[8] = {f2bf(a0.x), f2bf(a0.y), f2bf(a0.z), f2bf(a0.w),
                         f2bf(a1.x), f2bf(a1.y), f2bf(a1.z), f2bf(a1.w)};
  *(short8*)(Kb + (size_t)i * 8) = *(short8*)h;
}

// ---------------- prep: value -> bf16 transposed Vt[d][m] ----------------
__global__ void prep_vt(const float* __restrict__ value, unsigned short* __restrict__ Vt) {
  __shared__ float t[32][33];
  int tx = threadIdx.x & 31, ty = threadIdx.x >> 5;  // 32x8
  int m0 = blockIdx.x * 32;
  int d0 = blockIdx.y * 32;
#pragma unroll
  for (int i = 0; i < 4; ++i)
    t[ty + i * 8][tx] = value[(size_t)(m0 + ty + i * 8) * DVC + d0 + tx];
  __syncthreads();
#pragma unroll
  for (int i = 0; i < 4; ++i)
    Vt[(size_t)(d0 + ty + i * 8) * MK + m0 + tx] = f2bf(t[tx][ty + i * 8]);
}

// ---------------- gemm_s: S[4096][4096] bf16 = Qb * Kb^T (K=512) ----------------
__global__ __launch_bounds__(256, 3) void gemm_s(const unsigned short* __restrict__ Qb,
                                                 const unsigned short* __restrict__ Kb,
                                                 unsigned short* __restrict__ S) {
  __shared__ __align__(16) char lds[32768];  // A@0 (16K), B@16K (16K); epilogue reuses all
  const int tid = threadIdx.x;
  const int wid = tid >> 6, lane = tid & 63, lr = lane & 15, lh = lane >> 4;
  const int wm = wid >> 1, wn = wid & 1;

  int bid = blockIdx.x;                    // 1024 WGs, bijective XCD swizzle (1024%8==0)
  int swz = (bid & 7) * 128 + (bid >> 3);
  const int tm = swz >> 5, tn = swz & 31;
  const size_t m0 = (size_t)tm * 128, n0 = (size_t)tn * 128;

  f32x4 acc[4][4];
#pragma unroll
  for (int i = 0; i < 4; ++i)
#pragma unroll
    for (int j = 0; j < 4; ++j) acc[i][j] = (f32x4){0.f, 0.f, 0.f, 0.f};

  const char* abase = (const char*)Qb + m0 * 1024;  // row stride 1024 B
  const char* bbase = (const char*)Kb + n0 * 1024;

  for (int ks = 0; ks < 8; ++ks) {
    const int kb = ks * 128;  // 64 elems = 128 B per K-step
    {
      char* al = lds;
      char* bl = lds + 16384;
#pragma unroll
      for (int s = 0; s < 4; ++s) {
        int obase = wid * 4096 + s * 1024;  // wave-uniform LDS base; HW adds lane*16
        int o = obase + lane * 16;
        int row = o >> 7;                                 // 128 B per LDS row
        int colg = ((o >> 4) & 7) ^ (row & 7);            // inverse-swizzled source granule
        GLL16(abase + (size_t)row * 1024 + kb + colg * 16, al + obase);
        GLL16(bbase + (size_t)row * 1024 + kb + colg * 16, bl + obase);
      }
    }
    __syncthreads();
#pragma unroll
    for (int kk = 0; kk < 2; ++kk) {
      short8 af[4], bf[4];
#pragma unroll
      for (int i = 0; i < 4; ++i) {
        int ar = wm * 64 + i * 16 + lr;
        af[i] = *(const short8*)(lds + ar * 128 + ((((kk << 2) + lh) ^ (lr & 7)) << 4));
        int br = wn * 64 + i * 16 + lr;
        bf[i] = *(const short8*)(lds + 16384 + br * 128 + ((((kk << 2) + lh) ^ (lr & 7)) << 4));
      }
#pragma unroll
      for (int i = 0; i < 4; ++i)
#pragma unroll
        for (int j = 0; j < 4; ++j)
          acc[i][j] = __builtin_amdgcn_mfma_f32_16x16x32_bf16(af[i], bf[j], acc[i][j], 0, 0, 0);
    }
    __syncthreads();
  }

  // epilogue: bf16 bounce through LDS [128][128], then fully-coalesced 16B stores
  unsigned short* sl = (unsigned short*)lds;
#pragma unroll
  for (int i = 0; i < 4; ++i)
#pragma unroll
    for (int j = 0; j < 4; ++j)
#pragma unroll
      for (int r = 0; r < 4; ++r) {
        int m = wm * 64 + i * 16 + lh * 4 + r;
        int n = wn * 64 + j * 16 + lr;
        sl[m * 128 + n] = f2bf(acc[i][j][r]);
      }
  __syncthreads();
#pragma unroll
  for (int i = 0; i < 8; ++i) {
    int o = i * 4096 + tid * 16;
    int row = o >> 8, colb = o & 255;  // 256 B per bf16 tile row
    *(uint4*)((char*)S + (m0 + row) * 8192 + n0 * 2 + colb) = *(const uint4*)((const char*)sl + o);
  }
}

// ---------------- softmax_rows: in-place S -> P' = softmax_row/denom (bf16) ----------------
__global__ __launch_bounds__(256) void softmax_rows(unsigned short* __restrict__ S,
                                                    const float* __restrict__ qatt) {
  __shared__ float red[8];
  const int n = blockIdx.x;
  const int t = threadIdx.x;
  const int wv = t >> 6, lane = t & 63;
  unsigned short* row = S + (size_t)n * MK;
  short8 v0 = *(const short8*)(row + t * 16);
  short8 v1 = *(const short8*)(row + t * 16 + 8);
  float f[16];
#pragma unroll
  for (int j = 0; j < 8; ++j) {
    f[j] = bf2f((unsigned short)v0[j]) * SCALE;
    f[8 + j] = bf2f((unsigned short)v1[j]) * SCALE;
  }
  float mx = f[0];
#pragma unroll
  for (int j = 1; j < 16; ++j) mx = fmaxf(mx, f[j]);
#pragma unroll
  for (int off = 1; off < 64; off <<= 1) mx = fmaxf(mx, __shfl_xor(mx, off, 64));
  if (lane == 0) red[wv] = mx;
  __syncthreads();
  mx = fmaxf(fmaxf(red[0], red[1]), fmaxf(red[2], red[3]));
  float qa = qatt[n] * SCALE;
  mx = fmaxf(mx, qa);
  float e[16], s = 0.f;
#pragma unroll
  for (int j = 0; j < 16; ++j) {
    e[j] = __expf(f[j] - mx);
    s += e[j];
  }
#pragma unroll
  for (int off = 1; off < 64; off <<= 1) s += __shfl_xor(s, off, 64);
  if (lane == 0) red[4 + wv] = s;
  __syncthreads();
  float denom = red[4] + red[5] + red[6] + red[7] + __expf(qa - mx);
  float inv = 1.0f / denom;
  unsigned short h[16];
#pragma unroll
  for (int j = 0; j < 16; ++j) h[j] = f2bf(e[j] * inv);
  *(short8*)(row + t * 16) = *(short8*)h;
  *(short8*)(row + t * 16 + 8) = *(short8*)(h + 8);
}

// ---------------- gemm_o_part: part[ksl][4096][512] bf16 = P'(K-slice) * V ----------------
// Split-K=4. Tile 128m x 256n, BK=64, 8 waves (2wm x 4wn, 64x64 each, 4x4 acc
// -> 0.5 ds_read per MFMA), double-buffered LDS 96KB, counted vmcnt(6).
__global__ __launch_bounds__(512, 1) void gemm_o_part(const unsigned short* __restrict__ P,
                                                      const unsigned short* __restrict__ Vt,
                                                      unsigned short* __restrict__ part) {
  __shared__ __align__(16) char lds[98304];  // [A0 16K][B0 32K][A1 16K][B1 32K]
  const int tid = threadIdx.x;
  const int wid = tid >> 6, lane = tid & 63, lr = lane & 15, lh = lane >> 4;
  const int wm = wid >> 2, wn = wid & 3;  // 2 x 4 waves, each 64m x 64n

  int bid = blockIdx.x;                   // 256 WGs, bijective XCD swizzle
  int swz = (bid & 7) * 32 + (bid >> 3);
  const int ksl = swz & 3;                // 4 K-slices (1024 each)
  const int nt = (swz >> 2) & 1;          // 2 n-tiles of 256
  const int mt = swz >> 3;                // 32 m-tiles of 128
  const size_t m0 = (size_t)mt * 128, n0 = (size_t)nt * 256;

  f32x4 acc[4][4];
#pragma unroll
  for (int i = 0; i < 4; ++i)
#pragma unroll
    for (int j = 0; j < 4; ++j) acc[i][j] = (f32x4){0.f, 0.f, 0.f, 0.f};

  const char* abase = (const char*)P + m0 * 8192 + (size_t)ksl * 2048;   // P rows, K-slice
  const char* bbase = (const char*)Vt + n0 * 8192 + (size_t)ksl * 2048;  // Vt rows, K-slice

  // stage K-step ks into buffer b: A 128x64 bf16 (16KB, 128B rows) + B 256x64 (32KB)
  auto stage = [&](int ks, int b) {
    const int kb = ks * 128;  // 64 elems = 128 B
    char* al = lds + b * 49152;
    char* bl = al + 16384;
#pragma unroll
    for (int s = 0; s < 2; ++s) {  // A: 8 waves x 2KB
      int obase = wid * 2048 + s * 1024;
      int o = obase + lane * 16;
      int row = o >> 7;                            // 128 B per LDS row
      int colg = ((o >> 4) & 7) ^ (row & 7);       // inverse-swizzled source granule
      GLL16(abase + (size_t)row * 8192 + kb + colg * 16, al + obase);
    }
#pragma unroll
    for (int s = 0; s < 4; ++s) {  // B: 8 waves x 4KB
      int obase = wid * 4096 + s * 1024;
      int o = obase + lane * 16;
      int row = o >> 7;
      int colg = ((o >> 4) & 7) ^ (row & 7);
      GLL16(bbase + (size_t)row * 8192 + kb + colg * 16, bl + obase);
    }
  };

  stage(0, 0);  // prologue: 6 outstanding

  for (int ks = 0; ks < 16; ++ks) {
    const int cur = ks & 1;
    if (ks + 1 < 16) {
      stage(ks + 1, cur ^ 1);                           // 6 more in flight (12 total)
      asm volatile("s_waitcnt vmcnt(6)" ::: "memory");  // current step's 6 landed
    } else {
      asm volatile("s_waitcnt vmcnt(0)" ::: "memory");
    }
    __builtin_amdgcn_s_barrier();
    asm volatile("" ::: "memory");

    const char* al = lds + cur * 49152;
    const char* bl = al + 16384;
#pragma unroll
    for (int kk = 0; kk < 2; ++kk) {
      short8 af[4], bf[4];
#pragma unroll
      for (int i = 0; i < 4; ++i) {
        int ar = wm * 64 + i * 16 + lr;
        af[i] = *(const short8*)(al + ar * 128 + ((((kk << 2) + lh) ^ (lr & 7)) << 4));
        int br = wn * 64 + i * 16 + lr;
        bf[i] = *(const short8*)(bl + br * 128 + ((((kk << 2) + lh) ^ (lr & 7)) << 4));
      }
#pragma unroll
      for (int i = 0; i < 4; ++i)
#pragma unroll
        for (int j = 0; j < 4; ++j)
          acc[i][j] = __builtin_amdgcn_mfma_f32_16x16x32_bf16(af[i], bf[j], acc[i][j], 0, 0, 0);
    }

    asm volatile("" ::: "memory");
    __builtin_amdgcn_s_barrier();  // all waves done reading buf[cur] before overwrite
    asm volatile("" ::: "memory");
  }

  // epilogue: bf16 bounce [128][256] (64KB) + coalesced 16B stores to part[ksl]
  unsigned short* sl = (unsigned short*)lds;
#pragma unroll
  for (int i = 0; i < 4; ++i)
#pragma unroll
    for (int j = 0; j < 4; ++j)
#pragma unroll
      for (int r = 0; r < 4; ++r) {
        int m = wm * 64 + i * 16 + lh * 4 + r;
        int n = wn * 64 + j * 16 + lr;
        sl[m * 256 + n] = f2bf(acc[i][j][r]);
      }
  __builtin_amdgcn_s_barrier();
  asm volatile("" ::: "memory");
  char* pbase = (char*)part + (size_t)ksl * NQ * DVC * 2;
#pragma unroll
  for (int i = 0; i < 8; ++i) {
    int o = i * 8192 + tid * 16;
    int row = o >> 9, colb = o & 511;  // 512 B per bf16 tile row (256 elems)
    *(uint4*)(pbase + (m0 + row) * 1024 + n0 * 2 + colb) = *(const uint4*)((const char*)sl + o);
  }
}

// ---------------- combine_o: out = q_v*qa + sum(part[0..3]) ----------------
__global__ __launch_bounds__(256) void combine_o(const unsigned short* __restrict__ part,
                                                 const float* __restrict__ qatt,
                                                 const float* __restrict__ q_v,
                                                 float* __restrict__ out) {
  int idx = blockIdx.x * blockDim.x + threadIdx.x;  // one per 8 output elems
  int n = idx >> 6;
  int d8 = (idx & 63) * 8;
  float qa = qatt[n];
  size_t off = (size_t)n * DVC + d8;
  float r[8] = {0.f, 0.f, 0.f, 0.f, 0.f, 0.f, 0.f, 0.f};
#pragma unroll
  for (int w = 0; w < 4; ++w) {
    short8 po = *(const short8*)(part + (size_t)w * NQ * DVC + off);
#pragma unroll
    for (int j = 0; j < 8; ++j) r[j] += bf2f((unsigned short)po[j]);
  }
  const float4* qv = (const float4*)(q_v + off);
  float4 qv0 = qv[0], qv1 = qv[1];
  float4 o0 = {qv0.x * qa + r[0], qv0.y * qa + r[1], qv0.z * qa + r[2], qv0.w * qa + r[3]};
  float4 o1 = {qv1.x * qa + r[4], qv1.y * qa + r[5], qv1.z * qa + r[6], qv1.w * qa + r[7]};
  float4* op = (float4*)(out + off);
  op[0] = o0;
  op[1] = o1;
}

extern "C" void kernel_launch(void* const* d_in, const int* in_sizes, int n_in,
                              void* d_out, int out_size, void* d_ws, size_t ws_size,
                              hipStream_t stream) {
  const float* query = (const float*)d_in[0];
  const float* q_k = (const float*)d_in[1];
  const float* q_v = (const float*)d_in[2];
  const float* key = (const float*)d_in[3];
  const float* value = (const float*)d_in[4];
  float* out = (float*)d_out;

  char* ws = (char*)d_ws;
  unsigned short* Qb = (unsigned short*)(ws);                 // 4 MB
  unsigned short* Kb = (unsigned short*)(ws + (4u << 20));    // 4 MB
  unsigned short* Vt = (unsigned short*)(ws + (8u << 20));    // 4 MB
  unsigned short* S = (unsigned short*)(ws + (12u << 20));    // 32 MB (S, then P' in-place)
  float* qatt = (float*)(ws + (44u << 20));                   // 16 KB
  unsigned short* part = (unsigned short*)(ws + (45u << 20)); // 16 MB (4 x 4 MB bf16)

  prep_q<<<dim3(1024), dim3(256), 0, stream>>>(query, q_k, Qb, qatt);
  prep_k<<<dim3(1024), dim3(256), 0, stream>>>(key, Kb);
  prep_vt<<<dim3(128, 16), dim3(256), 0, stream>>>(value, Vt);
  gemm_s<<<dim3(1024), dim3(256), 0, stream>>>(Qb, Kb, S);
  softmax_rows<<<dim3(4096), dim3(256), 0, stream>>>(S, qatt);
  gemm_o_part<<<dim3(256), dim3(512), 0, stream>>>(S, Vt, part);
  combine_o<<<dim3(1024), dim3(256), 0, stream>>>(part, qatt, q_v, out);
}

// Round 8
// 70.435 us; speedup vs baseline: 1.2327x; 1.1730x over previous
//
#include <hip/hip_runtime.h>

#define NQ 4096
#define MK 4096
#define DKC 512
#define DVC 512
#define SCALE 0.044151079f  // 1/sqrt(513)

typedef __attribute__((ext_vector_type(8))) short short8;
typedef __attribute__((ext_vector_type(4))) float f32x4;

__device__ __forceinline__ unsigned short f2bf(float x) {
  unsigned u = __float_as_uint(x);
  u += 0x7fffu + ((u >> 16) & 1u);
  return (unsigned short)(u >> 16);
}
__device__ __forceinline__ float bf2f(unsigned short h) {
  return __uint_as_float((unsigned)h << 16);
}

#define GLL16(g, l)                                                        \
  __builtin_amdgcn_global_load_lds(                                        \
      (const __attribute__((address_space(1))) unsigned int*)(g),          \
      (__attribute__((address_space(3))) unsigned int*)(l), 16, 0, 0)

// ---------------- fused prep: Qb=bf16(q*SCALE)+qatt | Kb | Vt ----------------
// blocks [0,1024): query; [1024,2048): key; [2048,4096): value transpose
__global__ __launch_bounds__(256) void prep_all(const float* __restrict__ query,
                                                const float* __restrict__ q_k,
                                                const float* __restrict__ key,
                                                const float* __restrict__ value,
                                                unsigned short* __restrict__ Qb,
                                                unsigned short* __restrict__ Kb,
                                                unsigned short* __restrict__ Vt,
                                                float* __restrict__ qatt) {
  int b = blockIdx.x;
  if (b < 1024) {
    // query -> bf16 (prescaled by SCALE), q_att = rowdot(query, q_k) (raw)
    int n = b * 4 + (threadIdx.x >> 6);
    int lane = threadIdx.x & 63;
    const float4* qr = (const float4*)(query + (size_t)n * DKC + lane * 8);
    const float4* kr = (const float4*)(q_k + (size_t)n * DKC + lane * 8);
    float4 a0 = qr[0], a1 = qr[1];
    float4 b0 = kr[0], b1 = kr[1];
    float dot = a0.x * b0.x + a0.y * b0.y + a0.z * b0.z + a0.w * b0.w +
                a1.x * b1.x + a1.y * b1.y + a1.z * b1.z + a1.w * b1.w;
    unsigned short h[8] = {f2bf(a0.x * SCALE), f2bf(a0.y * SCALE), f2bf(a0.z * SCALE),
                           f2bf(a0.w * SCALE), f2bf(a1.x * SCALE), f2bf(a1.y * SCALE),
                           f2bf(a1.z * SCALE), f2bf(a1.w * SCALE)};
    *(short8*)(Qb + (size_t)n * DKC + lane * 8) = *(short8*)h;
#pragma unroll
    for (int off = 1; off < 64; off <<= 1) dot += __shfl_xor(dot, off, 64);
    if (lane == 0) qatt[n] = dot;
  } else if (b < 2048) {
    int i = (b - 1024) * 256 + threadIdx.x;  // one per 8 elements
    const float4* src = (const float4*)key + (size_t)i * 2;
    float4 a0 = src[0], a1 = src[1];
    unsigned short h[8] = {f2bf(a0.x), f2bf(a0.y), f2bf(a0.z), f2bf(a0.w),
                           f2bf(a1.x), f2bf(a1.y), f2bf(a1.z), f2bf(a1.w)};
    *(short8*)(Kb + (size_t)i * 8) = *(short8*)h;
  } else {
    __shared__ float t[32][33];
    int bi = b - 2048;
    int tx = threadIdx.x & 31, ty = threadIdx.x >> 5;  // 32x8
    int m0 = (bi & 127) * 32;
    int d0 = (bi >> 7) * 32;
#pragma unroll
    for (int i = 0; i < 4; ++i)
      t[ty + i * 8][tx] = value[(size_t)(m0 + ty + i * 8) * DVC + d0 + tx];
    __syncthreads();
#pragma unroll
    for (int i = 0; i < 4; ++i)
      Vt[(size_t)(d0 + ty + i * 8) * MK + m0 + tx] = f2bf(t[tx][ty + i * 8]);
  }
}

// ---------------- gemm_s: S[4096][4096] bf16 = exp(Qb * Kb^T)  (K=512) ----------------
// Qb prescaled by SCALE, so acc = s*SCALE; epilogue writes unnormalized exp.
__global__ __launch_bounds__(256, 3) void gemm_s(const unsigned short* __restrict__ Qb,
                                                 const unsigned short* __restrict__ Kb,
                                                 unsigned short* __restrict__ S) {
  __shared__ __align__(16) char lds[32768];  // A@0 (16K), B@16K (16K); epilogue reuses all
  const int tid = threadIdx.x;
  const int wid = tid >> 6, lane = tid & 63, lr = lane & 15, lh = lane >> 4;
  const int wm = wid >> 1, wn = wid & 1;

  int bid = blockIdx.x;                    // 1024 WGs, bijective XCD swizzle (1024%8==0)
  int swz = (bid & 7) * 128 + (bid >> 3);
  const int tm = swz >> 5, tn = swz & 31;
  const size_t m0 = (size_t)tm * 128, n0 = (size_t)tn * 128;

  f32x4 acc[4][4];
#pragma unroll
  for (int i = 0; i < 4; ++i)
#pragma unroll
    for (int j = 0; j < 4; ++j) acc[i][j] = (f32x4){0.f, 0.f, 0.f, 0.f};

  const char* abase = (const char*)Qb + m0 * 1024;  // row stride 1024 B
  const char* bbase = (const char*)Kb + n0 * 1024;

  for (int ks = 0; ks < 8; ++ks) {
    const int kb = ks * 128;  // 64 elems = 128 B per K-step
    {
      char* al = lds;
      char* bl = lds + 16384;
#pragma unroll
      for (int s = 0; s < 4; ++s) {
        int obase = wid * 4096 + s * 1024;  // wave-uniform LDS base; HW adds lane*16
        int o = obase + lane * 16;
        int row = o >> 7;                                 // 128 B per LDS row
        int colg = ((o >> 4) & 7) ^ (row & 7);            // inverse-swizzled source granule
        GLL16(abase + (size_t)row * 1024 + kb + colg * 16, al + obase);
        GLL16(bbase + (size_t)row * 1024 + kb + colg * 16, bl + obase);
      }
    }
    __syncthreads();
#pragma unroll
    for (int kk = 0; kk < 2; ++kk) {
      short8 af[4], bf[4];
#pragma unroll
      for (int i = 0; i < 4; ++i) {
        int ar = wm * 64 + i * 16 + lr;
        af[i] = *(const short8*)(lds + ar * 128 + ((((kk << 2) + lh) ^ (lr & 7)) << 4));
        int br = wn * 64 + i * 16 + lr;
        bf[i] = *(const short8*)(lds + 16384 + br * 128 + ((((kk << 2) + lh) ^ (lr & 7)) << 4));
      }
#pragma unroll
      for (int i = 0; i < 4; ++i)
#pragma unroll
        for (int j = 0; j < 4; ++j)
          acc[i][j] = __builtin_amdgcn_mfma_f32_16x16x32_bf16(af[i], bf[j], acc[i][j], 0, 0, 0);
    }
    __syncthreads();
  }

  // epilogue: P'' = exp(acc) bf16 bounce through LDS, coalesced 16B stores
  unsigned short* sl = (unsigned short*)lds;
#pragma unroll
  for (int i = 0; i < 4; ++i)
#pragma unroll
    for (int j = 0; j < 4; ++j)
#pragma unroll
      for (int r = 0; r < 4; ++r) {
        int m = wm * 64 + i * 16 + lh * 4 + r;
        int n = wn * 64 + j * 16 + lr;
        sl[m * 128 + n] = f2bf(__expf(acc[i][j][r]));
      }
  __syncthreads();
#pragma unroll
  for (int i = 0; i < 8; ++i) {
    int o = i * 4096 + tid * 16;
    int row = o >> 8, colb = o & 255;  // 256 B per bf16 tile row
    *(uint4*)((char*)S + (m0 + row) * 8192 + n0 * 2 + colb) = *(const uint4*)((const char*)sl + o);
  }
}

// ---------------- gemm_o_part: part[ksl][4096][512] bf16 = P''(K-slice) * V ----------------
// Split-K=4. Tile 128m x 256n, BK=64, 8 waves (2wm x 4wn, 64x64 each, 4x4 acc),
// double-buffered LDS 96KB, counted vmcnt(6).
__global__ __launch_bounds__(512, 1) void gemm_o_part(const unsigned short* __restrict__ P,
                                                      const unsigned short* __restrict__ Vt,
                                                      unsigned short* __restrict__ part) {
  __shared__ __align__(16) char lds[98304];  // [A0 16K][B0 32K][A1 16K][B1 32K]
  const int tid = threadIdx.x;
  const int wid = tid >> 6, lane = tid & 63, lr = lane & 15, lh = lane >> 4;
  const int wm = wid >> 2, wn = wid & 3;  // 2 x 4 waves, each 64m x 64n

  int bid = blockIdx.x;                   // 256 WGs, bijective XCD swizzle
  int swz = (bid & 7) * 32 + (bid >> 3);
  const int ksl = swz & 3;                // 4 K-slices (1024 each)
  const int nt = (swz >> 2) & 1;          // 2 n-tiles of 256
  const int mt = swz >> 3;                // 32 m-tiles of 128
  const size_t m0 = (size_t)mt * 128, n0 = (size_t)nt * 256;

  f32x4 acc[4][4];
#pragma unroll
  for (int i = 0; i < 4; ++i)
#pragma unroll
    for (int j = 0; j < 4; ++j) acc[i][j] = (f32x4){0.f, 0.f, 0.f, 0.f};

  const char* abase = (const char*)P + m0 * 8192 + (size_t)ksl * 2048;   // P rows, K-slice
  const char* bbase = (const char*)Vt + n0 * 8192 + (size_t)ksl * 2048;  // Vt rows, K-slice

  // stage K-step ks into buffer b: A 128x64 bf16 (16KB, 128B rows) + B 256x64 (32KB)
  auto stage = [&](int ks, int b) {
    const int kb = ks * 128;  // 64 elems = 128 B
    char* al = lds + b * 49152;
    char* bl = al + 16384;
#pragma unroll
    for (int s = 0; s < 2; ++s) {  // A: 8 waves x 2KB
      int obase = wid * 2048 + s * 1024;
      int o = obase + lane * 16;
      int row = o >> 7;                            // 128 B per LDS row
      int colg = ((o >> 4) & 7) ^ (row & 7);       // inverse-swizzled source granule
      GLL16(abase + (size_t)row * 8192 + kb + colg * 16, al + obase);
    }
#pragma unroll
    for (int s = 0; s < 4; ++s) {  // B: 8 waves x 4KB
      int obase = wid * 4096 + s * 1024;
      int o = obase + lane * 16;
      int row = o >> 7;
      int colg = ((o >> 4) & 7) ^ (row & 7);
      GLL16(bbase + (size_t)row * 8192 + kb + colg * 16, bl + obase);
    }
  };

  stage(0, 0);  // prologue: 6 outstanding

  for (int ks = 0; ks < 16; ++ks) {
    const int cur = ks & 1;
    if (ks + 1 < 16) {
      stage(ks + 1, cur ^ 1);                           // 6 more in flight (12 total)
      asm volatile("s_waitcnt vmcnt(6)" ::: "memory");  // current step's 6 landed
    } else {
      asm volatile("s_waitcnt vmcnt(0)" ::: "memory");
    }
    __builtin_amdgcn_s_barrier();
    asm volatile("" ::: "memory");

    const char* al = lds + cur * 49152;
    const char* bl = al + 16384;
#pragma unroll
    for (int kk = 0; kk < 2; ++kk) {
      short8 af[4], bf[4];
#pragma unroll
      for (int i = 0; i < 4; ++i) {
        int ar = wm * 64 + i * 16 + lr;
        af[i] = *(const short8*)(al + ar * 128 + ((((kk << 2) + lh) ^ (lr & 7)) << 4));
        int br = wn * 64 + i * 16 + lr;
        bf[i] = *(const short8*)(bl + br * 128 + ((((kk << 2) + lh) ^ (lr & 7)) << 4));
      }
#pragma unroll
      for (int i = 0; i < 4; ++i)
#pragma unroll
        for (int j = 0; j < 4; ++j)
          acc[i][j] = __builtin_amdgcn_mfma_f32_16x16x32_bf16(af[i], bf[j], acc[i][j], 0, 0, 0);
    }

    asm volatile("" ::: "memory");
    __builtin_amdgcn_s_barrier();  // all waves done reading buf[cur] before overwrite
    asm volatile("" ::: "memory");
  }

  // epilogue: bf16 bounce [128][256] (64KB) + coalesced 16B stores to part[ksl]
  unsigned short* sl = (unsigned short*)lds;
#pragma unroll
  for (int i = 0; i < 4; ++i)
#pragma unroll
    for (int j = 0; j < 4; ++j)
#pragma unroll
      for (int r = 0; r < 4; ++r) {
        int m = wm * 64 + i * 16 + lh * 4 + r;
        int n = wn * 64 + j * 16 + lr;
        sl[m * 256 + n] = f2bf(acc[i][j][r]);
      }
  __builtin_amdgcn_s_barrier();
  asm volatile("" ::: "memory");
  char* pbase = (char*)part + (size_t)ksl * NQ * DVC * 2;
#pragma unroll
  for (int i = 0; i < 8; ++i) {
    int o = i * 8192 + tid * 16;
    int row = o >> 9, colb = o & 511;  // 512 B per bf16 tile row (256 elems)
    *(uint4*)(pbase + (m0 + row) * 1024 + n0 * 2 + colb) = *(const uint4*)((const char*)sl + o);
  }
}

// ---------------- combine_row: per-row denom from P'' + epilogue ----------------
// out[n] = q_v[n]*qa + (sum_ksl part[ksl][n]) / (rowsum(P''[n]) + exp(qa*SCALE))
__global__ __launch_bounds__(256) void combine_row(const unsigned short* __restrict__ Ppp,
                                                   const unsigned short* __restrict__ part,
                                                   const float* __restrict__ qatt,
                                                   const float* __restrict__ q_v,
                                                   float* __restrict__ out) {
  __shared__ float red[4];
  const int n = blockIdx.x;
  const int t = threadIdx.x;
  const int wv = t >> 6, lane = t & 63;
  // phase A: rowsum of P''[n][0..4096)
  const unsigned short* row = Ppp + (size_t)n * MK;
  short8 v0 = *(const short8*)(row + t * 16);
  short8 v1 = *(const short8*)(row + t * 16 + 8);
  float s = 0.f;
#pragma unroll
  for (int j = 0; j < 8; ++j) s += bf2f((unsigned short)v0[j]) + bf2f((unsigned short)v1[j]);
#pragma unroll
  for (int off = 1; off < 64; off <<= 1) s += __shfl_xor(s, off, 64);
  if (lane == 0) red[wv] = s;
  __syncthreads();
  float qa = qatt[n];
  float denom = red[0] + red[1] + red[2] + red[3] + __expf(qa * SCALE);
  float inv = 1.0f / denom;
  // phase B: threads 0..63 produce the 512 outputs (8 each)
  if (t < 64) {
    size_t off = (size_t)n * DVC + t * 8;
    float r[8] = {0.f, 0.f, 0.f, 0.f, 0.f, 0.f, 0.f, 0.f};
#pragma unroll
    for (int w = 0; w < 4; ++w) {
      short8 po = *(const short8*)(part + (size_t)w * NQ * DVC + off);
#pragma unroll
      for (int j = 0; j < 8; ++j) r[j] += bf2f((unsigned short)po[j]);
    }
    const float4* qv = (const float4*)(q_v + off);
    float4 qv0 = qv[0], qv1 = qv[1];
    float4 o0 = {qv0.x * qa + r[0] * inv, qv0.y * qa + r[1] * inv, qv0.z * qa + r[2] * inv,
                 qv0.w * qa + r[3] * inv};
    float4 o1 = {qv1.x * qa + r[4] * inv, qv1.y * qa + r[5] * inv, qv1.z * qa + r[6] * inv,
                 qv1.w * qa + r[7] * inv};
    float4* op = (float4*)(out + off);
    op[0] = o0;
    op[1] = o1;
  }
}

extern "C" void kernel_launch(void* const* d_in, const int* in_sizes, int n_in,
                              void* d_out, int out_size, void* d_ws, size_t ws_size,
                              hipStream_t stream) {
  const float* query = (const float*)d_in[0];
  const float* q_k = (const float*)d_in[1];
  const float* q_v = (const float*)d_in[2];
  const float* key = (const float*)d_in[3];
  const float* value = (const float*)d_in[4];
  float* out = (float*)d_out;

  char* ws = (char*)d_ws;
  unsigned short* Qb = (unsigned short*)(ws);                 // 4 MB
  unsigned short* Kb = (unsigned short*)(ws + (4u << 20));    // 4 MB
  unsigned short* Vt = (unsigned short*)(ws + (8u << 20));    // 4 MB
  unsigned short* S = (unsigned short*)(ws + (12u << 20));    // 32 MB (holds P'' = exp)
  float* qatt = (float*)(ws + (44u << 20));                   // 16 KB
  unsigned short* part = (unsigned short*)(ws + (45u << 20)); // 16 MB (4 x 4 MB bf16)

  prep_all<<<dim3(4096), dim3(256), 0, stream>>>(query, q_k, key, value, Qb, Kb, Vt, qatt);
  gemm_s<<<dim3(1024), dim3(256), 0, stream>>>(Qb, Kb, S);
  gemm_o_part<<<dim3(256), dim3(512), 0, stream>>>(S, Vt, part);
  combine_row<<<dim3(4096), dim3(256), 0, stream>>>(S, part, qatt, q_v, out);
}

// Round 9
// 68.162 us; speedup vs baseline: 1.2738x; 1.0333x over previous
//
#include <hip/hip_runtime.h>

#define NQ 4096
#define MK 4096
#define DKC 512
#define DVC 512
#define SCALE 0.044151079f  // 1/sqrt(513)

typedef __attribute__((ext_vector_type(8))) short short8;
typedef __attribute__((ext_vector_type(4))) float f32x4;

__device__ __forceinline__ unsigned short f2bf(float x) {
  unsigned u = __float_as_uint(x);
  u += 0x7fffu + ((u >> 16) & 1u);
  return (unsigned short)(u >> 16);
}
__device__ __forceinline__ float bf2f(unsigned short h) {
  return __uint_as_float((unsigned)h << 16);
}

#define GLL16(g, l)                                                        \
  __builtin_amdgcn_global_load_lds(                                        \
      (const __attribute__((address_space(1))) unsigned int*)(g),          \
      (__attribute__((address_space(3))) unsigned int*)(l), 16, 0, 0)

// ---------------- fused prep: Qb=bf16(q*SCALE)+qatt | Kb | Vt ----------------
__global__ __launch_bounds__(256) void prep_all(const float* __restrict__ query,
                                                const float* __restrict__ q_k,
                                                const float* __restrict__ key,
                                                const float* __restrict__ value,
                                                unsigned short* __restrict__ Qb,
                                                unsigned short* __restrict__ Kb,
                                                unsigned short* __restrict__ Vt,
                                                float* __restrict__ qatt) {
  int b = blockIdx.x;
  if (b < 1024) {
    int n = b * 4 + (threadIdx.x >> 6);
    int lane = threadIdx.x & 63;
    const float4* qr = (const float4*)(query + (size_t)n * DKC + lane * 8);
    const float4* kr = (const float4*)(q_k + (size_t)n * DKC + lane * 8);
    float4 a0 = qr[0], a1 = qr[1];
    float4 b0 = kr[0], b1 = kr[1];
    float dot = a0.x * b0.x + a0.y * b0.y + a0.z * b0.z + a0.w * b0.w +
                a1.x * b1.x + a1.y * b1.y + a1.z * b1.z + a1.w * b1.w;
    unsigned short h[8] = {f2bf(a0.x * SCALE), f2bf(a0.y * SCALE), f2bf(a0.z * SCALE),
                           f2bf(a0.w * SCALE), f2bf(a1.x * SCALE), f2bf(a1.y * SCALE),
                           f2bf(a1.z * SCALE), f2bf(a1.w * SCALE)};
    *(short8*)(Qb + (size_t)n * DKC + lane * 8) = *(short8*)h;
#pragma unroll
    for (int off = 1; off < 64; off <<= 1) dot += __shfl_xor(dot, off, 64);
    if (lane == 0) qatt[n] = dot;
  } else if (b < 2048) {
    int i = (b - 1024) * 256 + threadIdx.x;
    const float4* src = (const float4*)key + (size_t)i * 2;
    float4 a0 = src[0], a1 = src[1];
    unsigned short h[8] = {f2bf(a0.x), f2bf(a0.y), f2bf(a0.z), f2bf(a0.w),
                           f2bf(a1.x), f2bf(a1.y), f2bf(a1.z), f2bf(a1.w)};
    *(short8*)(Kb + (size_t)i * 8) = *(short8*)h;
  } else {
    __shared__ float t[32][33];
    int bi = b - 2048;
    int tx = threadIdx.x & 31, ty = threadIdx.x >> 5;
    int m0 = (bi & 127) * 32;
    int d0 = (bi >> 7) * 32;
#pragma unroll
    for (int i = 0; i < 4; ++i)
      t[ty + i * 8][tx] = value[(size_t)(m0 + ty + i * 8) * DVC + d0 + tx];
    __syncthreads();
#pragma unroll
    for (int i = 0; i < 4; ++i)
      Vt[(size_t)(d0 + ty + i * 8) * MK + m0 + tx] = f2bf(t[tx][ty + i * 8]);
  }
}

// ---------------- gemm_s: P''[4096][4096] bf16 = exp(Qb * Kb^T) + row-partial sums ----
// Qb prescaled by SCALE. 4 blocks/CU (no tail). Epilogue also emits
// rowsum_part[tn][4096] = sum over this block's 128 cols of exp.
__global__ __launch_bounds__(256, 4) void gemm_s(const unsigned short* __restrict__ Qb,
                                                 const unsigned short* __restrict__ Kb,
                                                 unsigned short* __restrict__ S,
                                                 float* __restrict__ rowsum_part) {
  __shared__ __align__(16) char lds[33792];  // staging 32K; epilogue: sl 32K + rs 1K
  const int tid = threadIdx.x;
  const int wid = tid >> 6, lane = tid & 63, lr = lane & 15, lh = lane >> 4;
  const int wm = wid >> 1, wn = wid & 1;

  int bid = blockIdx.x;                    // 1024 WGs, bijective XCD swizzle
  int swz = (bid & 7) * 128 + (bid >> 3);
  const int tm = swz >> 5, tn = swz & 31;
  const size_t m0 = (size_t)tm * 128, n0 = (size_t)tn * 128;

  f32x4 acc[4][4];
#pragma unroll
  for (int i = 0; i < 4; ++i)
#pragma unroll
    for (int j = 0; j < 4; ++j) acc[i][j] = (f32x4){0.f, 0.f, 0.f, 0.f};

  const char* abase = (const char*)Qb + m0 * 1024;  // row stride 1024 B
  const char* bbase = (const char*)Kb + n0 * 1024;

  for (int ks = 0; ks < 8; ++ks) {
    const int kb = ks * 128;
    {
      char* al = lds;
      char* bl = lds + 16384;
#pragma unroll
      for (int s = 0; s < 4; ++s) {
        int obase = wid * 4096 + s * 1024;
        int o = obase + lane * 16;
        int row = o >> 7;
        int colg = ((o >> 4) & 7) ^ (row & 7);
        GLL16(abase + (size_t)row * 1024 + kb + colg * 16, al + obase);
        GLL16(bbase + (size_t)row * 1024 + kb + colg * 16, bl + obase);
      }
    }
    __syncthreads();
#pragma unroll
    for (int kk = 0; kk < 2; ++kk) {
      short8 af[4], bf[4];
#pragma unroll
      for (int i = 0; i < 4; ++i) {
        int ar = wm * 64 + i * 16 + lr;
        af[i] = *(const short8*)(lds + ar * 128 + ((((kk << 2) + lh) ^ (lr & 7)) << 4));
        int br = wn * 64 + i * 16 + lr;
        bf[i] = *(const short8*)(lds + 16384 + br * 128 + ((((kk << 2) + lh) ^ (lr & 7)) << 4));
      }
#pragma unroll
      for (int i = 0; i < 4; ++i)
#pragma unroll
        for (int j = 0; j < 4; ++j)
          acc[i][j] = __builtin_amdgcn_mfma_f32_16x16x32_bf16(af[i], bf[j], acc[i][j], 0, 0, 0);
    }
    __syncthreads();
  }

  // epilogue: e = exp(acc); pack to LDS; accumulate per-row sums in registers
  unsigned short* sl = (unsigned short*)lds;
  float* rs = (float*)(lds + 32768);  // [2][128] cross-wave rowsum partials
  float rsum[4][4];
#pragma unroll
  for (int i = 0; i < 4; ++i)
#pragma unroll
    for (int r = 0; r < 4; ++r) rsum[i][r] = 0.f;
#pragma unroll
  for (int i = 0; i < 4; ++i)
#pragma unroll
    for (int j = 0; j < 4; ++j)
#pragma unroll
      for (int r = 0; r < 4; ++r) {
        int m = wm * 64 + i * 16 + lh * 4 + r;
        int n = wn * 64 + j * 16 + lr;
        float e = __expf(acc[i][j][r]);
        sl[m * 128 + n] = f2bf(e);
        rsum[i][r] += e;
      }
  // reduce over the 16 col-lanes (lr), lanes of same lh group
#pragma unroll
  for (int i = 0; i < 4; ++i)
#pragma unroll
    for (int r = 0; r < 4; ++r) {
      float v = rsum[i][r];
      v += __shfl_xor(v, 1, 64);
      v += __shfl_xor(v, 2, 64);
      v += __shfl_xor(v, 4, 64);
      v += __shfl_xor(v, 8, 64);
      if (lr == 0) rs[wn * 128 + wm * 64 + i * 16 + lh * 4 + r] = v;
    }
  __syncthreads();
  if (tid < 128) rowsum_part[(size_t)tn * NQ + m0 + tid] = rs[tid] + rs[128 + tid];
#pragma unroll
  for (int i = 0; i < 8; ++i) {
    int o = i * 4096 + tid * 16;
    int row = o >> 8, colb = o & 255;
    *(uint4*)((char*)S + (m0 + row) * 8192 + n0 * 2 + colb) = *(const uint4*)((const char*)sl + o);
  }
}

// ---------------- gemm_o_part: part[ksl][4096][512] bf16 = P''(K-slice) * V ----------------
__global__ __launch_bounds__(512, 1) void gemm_o_part(const unsigned short* __restrict__ P,
                                                      const unsigned short* __restrict__ Vt,
                                                      unsigned short* __restrict__ part) {
  __shared__ __align__(16) char lds[98304];  // [A0 16K][B0 32K][A1 16K][B1 32K]
  const int tid = threadIdx.x;
  const int wid = tid >> 6, lane = tid & 63, lr = lane & 15, lh = lane >> 4;
  const int wm = wid >> 2, wn = wid & 3;  // 2 x 4 waves, each 64m x 64n

  int bid = blockIdx.x;
  int swz = (bid & 7) * 32 + (bid >> 3);
  const int ksl = swz & 3;
  const int nt = (swz >> 2) & 1;
  const int mt = swz >> 3;
  const size_t m0 = (size_t)mt * 128, n0 = (size_t)nt * 256;

  f32x4 acc[4][4];
#pragma unroll
  for (int i = 0; i < 4; ++i)
#pragma unroll
    for (int j = 0; j < 4; ++j) acc[i][j] = (f32x4){0.f, 0.f, 0.f, 0.f};

  const char* abase = (const char*)P + m0 * 8192 + (size_t)ksl * 2048;
  const char* bbase = (const char*)Vt + n0 * 8192 + (size_t)ksl * 2048;

  auto stage = [&](int ks, int b) {
    const int kb = ks * 128;
    char* al = lds + b * 49152;
    char* bl = al + 16384;
#pragma unroll
    for (int s = 0; s < 2; ++s) {
      int obase = wid * 2048 + s * 1024;
      int o = obase + lane * 16;
      int row = o >> 7;
      int colg = ((o >> 4) & 7) ^ (row & 7);
      GLL16(abase + (size_t)row * 8192 + kb + colg * 16, al + obase);
    }
#pragma unroll
    for (int s = 0; s < 4; ++s) {
      int obase = wid * 4096 + s * 1024;
      int o = obase + lane * 16;
      int row = o >> 7;
      int colg = ((o >> 4) & 7) ^ (row & 7);
      GLL16(bbase + (size_t)row * 8192 + kb + colg * 16, bl + obase);
    }
  };

  stage(0, 0);

  for (int ks = 0; ks < 16; ++ks) {
    const int cur = ks & 1;
    if (ks + 1 < 16) {
      stage(ks + 1, cur ^ 1);
      asm volatile("s_waitcnt vmcnt(6)" ::: "memory");
    } else {
      asm volatile("s_waitcnt vmcnt(0)" ::: "memory");
    }
    __builtin_amdgcn_s_barrier();
    asm volatile("" ::: "memory");

    const char* al = lds + cur * 49152;
    const char* bl = al + 16384;
#pragma unroll
    for (int kk = 0; kk < 2; ++kk) {
      short8 af[4], bf[4];
#pragma unroll
      for (int i = 0; i < 4; ++i) {
        int ar = wm * 64 + i * 16 + lr;
        af[i] = *(const short8*)(al + ar * 128 + ((((kk << 2) + lh) ^ (lr & 7)) << 4));
        int br = wn * 64 + i * 16 + lr;
        bf[i] = *(const short8*)(bl + br * 128 + ((((kk << 2) + lh) ^ (lr & 7)) << 4));
      }
#pragma unroll
      for (int i = 0; i < 4; ++i)
#pragma unroll
        for (int j = 0; j < 4; ++j)
          acc[i][j] = __builtin_amdgcn_mfma_f32_16x16x32_bf16(af[i], bf[j], acc[i][j], 0, 0, 0);
    }

    asm volatile("" ::: "memory");
    __builtin_amdgcn_s_barrier();
    asm volatile("" ::: "memory");
  }

  unsigned short* sl = (unsigned short*)lds;
#pragma unroll
  for (int i = 0; i < 4; ++i)
#pragma unroll
    for (int j = 0; j < 4; ++j)
#pragma unroll
      for (int r = 0; r < 4; ++r) {
        int m = wm * 64 + i * 16 + lh * 4 + r;
        int n = wn * 64 + j * 16 + lr;
        sl[m * 256 + n] = f2bf(acc[i][j][r]);
      }
  __builtin_amdgcn_s_barrier();
  asm volatile("" ::: "memory");
  char* pbase = (char*)part + (size_t)ksl * NQ * DVC * 2;
#pragma unroll
  for (int i = 0; i < 8; ++i) {
    int o = i * 8192 + tid * 16;
    int row = o >> 9, colb = o & 511;
    *(uint4*)(pbase + (m0 + row) * 1024 + n0 * 2 + colb) = *(const uint4*)((const char*)sl + o);
  }
}

// ---------------- row_inv: inv[n] = 1 / (sum_tn rowsum_part[tn][n] + exp(qa*SCALE)) ----
__global__ __launch_bounds__(256) void row_inv(const float* __restrict__ rowsum_part,
                                               const float* __restrict__ qatt,
                                               float* __restrict__ inv) {
  int n = blockIdx.x * 256 + threadIdx.x;
  float s = 0.f;
#pragma unroll
  for (int tn = 0; tn < 32; ++tn) s += rowsum_part[(size_t)tn * NQ + n];
  inv[n] = 1.0f / (s + __expf(qatt[n] * SCALE));
}

// ---------------- combine2: out = q_v*qa + (sum_ksl part[ksl]) * inv[n] ----------------
__global__ __launch_bounds__(256) void combine2(const unsigned short* __restrict__ part,
                                                const float* __restrict__ qatt,
                                                const float* __restrict__ inv,
                                                const float* __restrict__ q_v,
                                                float* __restrict__ out) {
  int idx = blockIdx.x * blockDim.x + threadIdx.x;  // one per 8 output elems
  int n = idx >> 6;
  int d8 = (idx & 63) * 8;
  float qa = qatt[n];
  float iv = inv[n];
  size_t off = (size_t)n * DVC + d8;
  float r[8] = {0.f, 0.f, 0.f, 0.f, 0.f, 0.f, 0.f, 0.f};
#pragma unroll
  for (int w = 0; w < 4; ++w) {
    short8 po = *(const short8*)(part + (size_t)w * NQ * DVC + off);
#pragma unroll
    for (int j = 0; j < 8; ++j) r[j] += bf2f((unsigned short)po[j]);
  }
  const float4* qv = (const float4*)(q_v + off);
  float4 qv0 = qv[0], qv1 = qv[1];
  float4 o0 = {qv0.x * qa + r[0] * iv, qv0.y * qa + r[1] * iv, qv0.z * qa + r[2] * iv,
               qv0.w * qa + r[3] * iv};
  float4 o1 = {qv1.x * qa + r[4] * iv, qv1.y * qa + r[5] * iv, qv1.z * qa + r[6] * iv,
               qv1.w * qa + r[7] * iv};
  float4* op = (float4*)(out + off);
  op[0] = o0;
  op[1] = o1;
}

extern "C" void kernel_launch(void* const* d_in, const int* in_sizes, int n_in,
                              void* d_out, int out_size, void* d_ws, size_t ws_size,
                              hipStream_t stream) {
  const float* query = (const float*)d_in[0];
  const float* q_k = (const float*)d_in[1];
  const float* q_v = (const float*)d_in[2];
  const float* key = (const float*)d_in[3];
  const float* value = (const float*)d_in[4];
  float* out = (float*)d_out;

  char* ws = (char*)d_ws;
  unsigned short* Qb = (unsigned short*)(ws);                 // 4 MB
  unsigned short* Kb = (unsigned short*)(ws + (4u << 20));    // 4 MB
  unsigned short* Vt = (unsigned short*)(ws + (8u << 20));    // 4 MB
  unsigned short* S = (unsigned short*)(ws + (12u << 20));    // 32 MB (holds P'' = exp)
  float* qatt = (float*)(ws + (44u << 20));                   // 16 KB
  unsigned short* part = (unsigned short*)(ws + (45u << 20)); // 16 MB (4 x 4 MB bf16)
  float* rowsum_part = (float*)(ws + (61u << 20));            // 512 KB (32 x 4096 f32)
  float* inv = (float*)(ws + (62u << 20));                    // 16 KB

  prep_all<<<dim3(4096), dim3(256), 0, stream>>>(query, q_k, key, value, Qb, Kb, Vt, qatt);
  gemm_s<<<dim3(1024), dim3(256), 0, stream>>>(Qb, Kb, S, rowsum_part);
  gemm_o_part<<<dim3(256), dim3(512), 0, stream>>>(S, Vt, part);
  row_inv<<<dim3(16), dim3(256), 0, stream>>>(rowsum_part, qatt, inv);
  combine2<<<dim3(1024), dim3(256), 0, stream>>>(part, qatt, inv, q_v, out);
}